// Round 14
// baseline (48.515 us; speedup 1.0000x reference)
//
#include <hip/hip_runtime.h>
#include <math.h>

#define Bb 4
#define Nn 4096
#define Hh 128
#define Ff 64
#define CAP 128  // max neighbors kept per row (deg ~41 +/- 6.4; 13 sigma)

typedef __attribute__((ext_vector_type(8))) short bf16x8;
typedef __attribute__((ext_vector_type(4))) float f32x4;

// bf16 helpers (RNE)
__device__ __forceinline__ unsigned short f2bf(float f) {
  unsigned int u = __float_as_uint(f);
  u += 0x7fffu + ((u >> 16) & 1u);
  return (unsigned short)(u >> 16);
}
__device__ __forceinline__ float bf2f(unsigned short h) {
  return __uint_as_float(((unsigned int)h) << 16);
}

// ---------------------------------------------------------------------------
// prep_kernel, 1280 blocks — TLP A/B vs R13 (46.8us; R13 had 768 blocks =
// 3/CU). Same two verified role bodies; only the grid shape changes:
//   bid % 5 == 4  -> QKV block  (256 total, 64 rows each; R8-verified MFMA)
//   else          -> CSR block  (1024 total, 4 rows each, ONE row per wave,
//                    16-deep hoisted float4 stream + parallel scan)
// Fine interleave => every CU hosts a heterogeneous mix (~5 blocks/CU,
// ~20 waves/CU) => ~2.5x the outstanding loads of R13. Every slow profile
// this session showed nothing-saturated latency starvation (VALU<=22%,
// HBM<=1TB/s, occ 13-31%); this is the direct test. If total doesn't move,
// TLP is falsified and the bottleneck is memory-system contention.
// ---------------------------------------------------------------------------
__global__ __launch_bounds__(256) void prep_kernel(
    const float* __restrict__ x,
    const float* __restrict__ Wq,
    const float* __restrict__ Wk,
    const float* __restrict__ Wv,
    const float* __restrict__ adj,
    float* __restrict__ q,
    unsigned short* __restrict__ kb,
    unsigned short* __restrict__ vb,
    unsigned short* __restrict__ g_nbr, int* __restrict__ g_cnt) {
  __shared__ short xs[64 * 128];  // 16KB bf16, swizzled (QKV role only)
  __shared__ __align__(8) unsigned short stg[4][CAP];  // 1KB (CSR role)

  const int tid = threadIdx.x;
  const int w = tid >> 6;
  const int lane = tid & 63;
  const int bid = (int)blockIdx.x;

  if ((bid % 5) == 4) {
    // ---------------- QKV via MFMA (R8 verbatim) ----------------
    const int row0 = (bid / 5) * 64;
    const int half = lane >> 4;  // 0..3
    const int l16 = lane & 15;

    const float4* xg = (const float4*)(x + (size_t)row0 * Hh);
#pragma unroll
    for (int j = 0; j < 8; ++j) {
      const int idx = tid + 256 * j;  // float4 index; 32 per row
      const int row = idx >> 5;
      const int c4 = idx & 31;
      const float4 xv = xg[idx];
      uint2 p;
      p.x = (unsigned)f2bf(xv.x) | ((unsigned)f2bf(xv.y) << 16);
      p.y = (unsigned)f2bf(xv.z) | ((unsigned)f2bf(xv.w) << 16);
      const int addr = (row * 256 + c4 * 8) ^ ((row & 7) << 4);
      *(uint2*)((char*)xs + addr) = p;
    }

    bf16x8 bfr[3][4];
#pragma unroll
    for (int nt = 0; nt < 3; ++nt) {
      const int n0g = w * 48 + nt * 16;
      const float* Wm = (n0g < 64) ? Wq : (n0g < 128) ? Wk : Wv;
      const int c0 = n0g & 63;
#pragma unroll
      for (int ks = 0; ks < 4; ++ks) {
        bf16x8 f;
#pragma unroll
        for (int j = 0; j < 8; ++j) {
          const int kr = ks * 32 + half * 8 + j;
          f[j] = (short)f2bf(Wm[kr * Ff + c0 + l16]);
        }
        bfr[nt][ks] = f;
      }
    }
    __syncthreads();

    f32x4 acc[4][3];
#pragma unroll
    for (int mt = 0; mt < 4; ++mt)
#pragma unroll
      for (int nt = 0; nt < 3; ++nt)
#pragma unroll
        for (int r = 0; r < 4; ++r) acc[mt][nt][r] = 0.f;

#pragma unroll
    for (int mt = 0; mt < 4; ++mt) {
      const int arow = mt * 16 + l16;
      const int abase = arow * 256;
      const int aswz = (arow & 7) << 4;
#pragma unroll
      for (int ks = 0; ks < 4; ++ks) {
        const int addr = (abase + ks * 64 + half * 16) ^ aswz;
        const bf16x8 a = *(const bf16x8*)((const char*)xs + addr);
#pragma unroll
        for (int nt = 0; nt < 3; ++nt) {
          acc[mt][nt] = __builtin_amdgcn_mfma_f32_16x16x32_bf16(
              a, bfr[nt][ks], acc[mt][nt], 0, 0, 0);
        }
      }
    }

#pragma unroll
    for (int mt = 0; mt < 4; ++mt) {
#pragma unroll
      for (int nt = 0; nt < 3; ++nt) {
        const int n0g = w * 48 + nt * 16;
        const int col = (n0g & 63) + l16;
#pragma unroll
        for (int r = 0; r < 4; ++r) {
          const size_t rowg = (size_t)row0 + mt * 16 + half * 4 + r;
          const float val = acc[mt][nt][r];
          if (n0g < 64)
            q[rowg * Ff + col] = val;
          else if (n0g < 128)
            kb[rowg * Ff + col] = f2bf(val);
          else
            vb[rowg * Ff + col] = f2bf(val);
        }
      }
    }
  } else {
    // ------- adj -> CSR: ONE row per wave, parallel scan (R13 body) -------
    const int csr_idx = (bid / 5) * 4 + (bid % 5);  // [0,1024) bijective
    const int n = csr_idx * 4 + w;
    const float4* ap = (const float4*)(adj + (size_t)n * Nn);
    unsigned short* srow = stg[w];

    // deterministic tail: zero-init staging row (1 ushort2/lane)
    ((ushort2*)srow)[lane] = make_ushort2(0, 0);

    float4 a4[16];  // hoisted: 16 outstanding loads per lane
#pragma unroll
    for (int j = 0; j < 16; ++j) a4[j] = ap[j * 64 + lane];

    int cnt = 0;
#pragma unroll
    for (int j = 0; j < 16; ++j) {
      cnt += (a4[j].x != 0.f) + (a4[j].y != 0.f) + (a4[j].z != 0.f) +
             (a4[j].w != 0.f);
    }

    int inc = cnt;  // wave inclusive scan (6 steps)
#pragma unroll
    for (int o = 1; o < 64; o <<= 1) {
      const int t = __shfl_up(inc, o, 64);
      if (lane >= o) inc += t;
    }

    int pos = inc - cnt;  // exclusive offset
#pragma unroll
    for (int j = 0; j < 16; ++j) {
      const int col0 = 4 * (j * 64 + lane);
#pragma unroll
      for (int comp = 0; comp < 4; ++comp) {
        const float val = comp == 0 ? a4[j].x
                        : comp == 1 ? a4[j].y
                        : comp == 2 ? a4[j].z
                                    : a4[j].w;
        if (val != 0.f) {
          if (pos < CAP) srow[pos] = (unsigned short)(col0 + comp);
          ++pos;
        }
      }
    }

    const int tot = __shfl(inc, 63, 64);
    if (lane == 0) g_cnt[n] = tot < CAP ? tot : CAP;
    // one coalesced 256B writeout (same-wave LDS write->read, lgkmcnt ok)
    ((ushort2*)(g_nbr + (size_t)n * CAP))[lane] = ((const ushort2*)srow)[lane];
  }
}

// ---------------------------------------------------------------------------
// attn_kernel: sparse masked attention over CSR, bf16 k/v (verified, ~5us).
// One block (4 waves) per row n; wave w = batch b.
// Score: 4-lane-group k gather, line-minimal (bf16 row = 128B = 2 lines).
//   Group shfl(1,2) completes the dot; all 4 lanes hold identical s -> tile
//   psum reduce spans GROUPS ONLY (offsets 32..4; 2,1 would 4x-count: R3 bug).
// PV: lane = feature, p broadcast from LDS.
// out = acc/L + sum_v (reference adds adj back: +1 per neighbor).
// ---------------------------------------------------------------------------
__global__ __launch_bounds__(256) void attn_kernel(
    const unsigned short* __restrict__ g_nbr,
    const int* __restrict__ g_cnt,
    const float* __restrict__ q,
    const unsigned short* __restrict__ kb,
    const unsigned short* __restrict__ vb,
    float* __restrict__ out) {
  __shared__ __align__(8) unsigned short nbr[CAP];
  __shared__ float qs[4][64];
  __shared__ float ps[4][64];

  const int n = blockIdx.x;
  const int tid = threadIdx.x;
  const int w = tid >> 6;
  const int lane = tid & 63;

  qs[w][lane] = q[((size_t)w * Nn + n) * Ff + lane];
  if (w == 0) {
    ((ushort2*)nbr)[lane] = ((const ushort2*)(g_nbr + (size_t)n * CAP))[lane];
  }
  const int tot = g_cnt[n];
  __syncthreads();

  const int b = w;
  const unsigned short* kbb = kb + (size_t)b * Nn * Ff;
  const unsigned short* vbb = vb + (size_t)b * Nn * Ff;

  const int g = lane >> 2;  // row group 0..15
  const int sl = lane & 3;  // sub-lane

  float4 q0a = *(const float4*)&qs[b][8 * sl];
  float4 q0b = *(const float4*)&qs[b][8 * sl + 4];
  float4 q1a = *(const float4*)&qs[b][32 + 8 * sl];
  float4 q1b = *(const float4*)&qs[b][32 + 8 * sl + 4];

  float M = -INFINITY, L = 0.f, acc = 0.f, vsum = 0.f;

  const int ntiles = (tot + 63) >> 6;
  for (int t = 0; t < ntiles; ++t) {
    const int tbase = t << 6;

    float s0, s1, s2, s3;
#define BPAIR(u, qlo, qhi, a)                                   \
    {                                                           \
      const float flo = __uint_as_float((u) << 16);             \
      const float fhi = __uint_as_float((u) & 0xffff0000u);     \
      a = fmaf(qlo, flo, a);                                    \
      a = fmaf(qhi, fhi, a);                                    \
    }
#define DOT_ROW(i, sdst)                                                  \
    {                                                                     \
      const int idx = tbase + g + 16 * (i);                               \
      const bool valid = idx < tot;                                       \
      const int m = valid ? (int)nbr[idx] : 0;                            \
      const char* krow = (const char*)(kbb + (size_t)m * Ff);             \
      const uint4 k0 = *(const uint4*)(krow + 16 * sl);                   \
      const uint4 k1 = *(const uint4*)(krow + 64 + 16 * sl);              \
      float a = 0.f;                                                      \
      BPAIR(k0.x, q0a.x, q0a.y, a)                                        \
      BPAIR(k0.y, q0a.z, q0a.w, a)                                        \
      BPAIR(k0.z, q0b.x, q0b.y, a)                                        \
      BPAIR(k0.w, q0b.z, q0b.w, a)                                        \
      BPAIR(k1.x, q1a.x, q1a.y, a)                                        \
      BPAIR(k1.y, q1a.z, q1a.w, a)                                        \
      BPAIR(k1.z, q1b.x, q1b.y, a)                                        \
      BPAIR(k1.w, q1b.z, q1b.w, a)                                        \
      a += __shfl_xor(a, 1, 64);                                          \
      a += __shfl_xor(a, 2, 64);                                          \
      sdst = valid ? a * 0.125f : -INFINITY;                              \
    }
    DOT_ROW(0, s0)
    DOT_ROW(1, s1)
    DOT_ROW(2, s2)
    DOT_ROW(3, s3)
#undef DOT_ROW
#undef BPAIR

    float lm = fmaxf(fmaxf(s0, s1), fmaxf(s2, s3));
#pragma unroll
    for (int o = 32; o; o >>= 1) lm = fmaxf(lm, __shfl_xor(lm, o, 64));
    const float newM = fmaxf(M, lm);

    const float p0 = (s0 == -INFINITY) ? 0.f : __expf(s0 - newM);
    const float p1 = (s1 == -INFINITY) ? 0.f : __expf(s1 - newM);
    const float p2 = (s2 == -INFINITY) ? 0.f : __expf(s2 - newM);
    const float p3 = (s3 == -INFINITY) ? 0.f : __expf(s3 - newM);

    float psum = ((p0 + p1) + (p2 + p3));
#pragma unroll
    for (int o = 32; o >= 4; o >>= 1) psum += __shfl_xor(psum, o, 64);

    const float corr = __expf(M - newM);  // t==0: exp(-inf)=0, L=acc=0
    L = L * corr + psum;
    acc *= corr;
    M = newM;

    const float pw = sl == 0 ? p0 : sl == 1 ? p1 : sl == 2 ? p2 : p3;
    ps[w][g + 16 * sl] = pw;

    const int jmax = min(64, tot - tbase);
#pragma unroll 4
    for (int j = 0; j < jmax; ++j) {
      const int m = nbr[tbase + j];                       // LDS broadcast
      const float vf = bf2f(vbb[(size_t)m * Ff + lane]);  // coalesced 128B
      acc = fmaf(ps[w][j], vf, acc);                      // p broadcast
      vsum += vf;
    }
  }

  out[((size_t)b * Nn + n) * Ff + lane] = acc / L + vsum;
}

// ---------------------------------------------------------------------------
extern "C" void kernel_launch(void* const* d_in, const int* in_sizes, int n_in,
                              void* d_out, int out_size, void* d_ws, size_t ws_size,
                              hipStream_t stream) {
  const float* x = (const float*)d_in[0];
  const float* Wq = (const float*)d_in[1];
  const float* Wk = (const float*)d_in[2];
  const float* Wv = (const float*)d_in[3];
  const float* adj = (const float*)d_in[4];
  float* out = (float*)d_out;

  char* ws = (char*)d_ws;
  const size_t rows = (size_t)Bb * Nn;  // 16384
  float* q = (float*)ws;                                       // 4 MiB
  unsigned short* kb = (unsigned short*)(ws + rows * Ff * 4);  // 2 MiB
  unsigned short* vb = (unsigned short*)(ws + rows * Ff * 4 + rows * Ff * 2);
  unsigned short* g_nbr = (unsigned short*)(ws + rows * Ff * 8);  // 1 MiB
  int* g_cnt = (int*)(ws + rows * Ff * 8 + (size_t)Nn * CAP * 2);

  prep_kernel<<<dim3(1280), dim3(256), 0, stream>>>(
      x, Wq, Wk, Wv, adj, q, kb, vb, g_nbr, g_cnt);
  attn_kernel<<<dim3(Nn), dim3(256), 0, stream>>>(g_nbr, g_cnt, q, kb, vb, out);
}

// Round 15
// 47.380 us; speedup vs baseline: 1.0240x; 1.0240x over previous
//
#include <hip/hip_runtime.h>
#include <math.h>

#define Bb 4
#define Nn 4096
#define Hh 128
#define Ff 64
#define CAP 128  // max neighbors kept per row (deg ~41 +/- 6.4; 13 sigma)

typedef __attribute__((ext_vector_type(8))) short bf16x8;
typedef __attribute__((ext_vector_type(4))) float f32x4;

// bf16 helpers (RNE)
__device__ __forceinline__ unsigned short f2bf(float f) {
  unsigned int u = __float_as_uint(f);
  u += 0x7fffu + ((u >> 16) & 1u);
  return (unsigned short)(u >> 16);
}
__device__ __forceinline__ float bf2f(unsigned short h) {
  return __uint_as_float(((unsigned int)h) << 16);
}

// ---------------------------------------------------------------------------
// prep2_kernel, 2304 blocks: R8's heterogeneous packing with the CSR scan
// replaced by a PURE bitmask stream (the decisive experiment: across R8-R14,
// {scan+qkv} = ~40us invariant; models say ~15. This kernel strips the scan
// to load->ballot->store only — if it still runs ~2TB/s, that's the
// platform's ceiling for this pattern, measured clean).
//   bid <  256 : QKV via bf16 MFMA, 64 rows (R8-verified verbatim).
//   bid >= 256 : bitmask stream. 2048 blocks x 4 waves, 8 chunks/wave
//     (1 chunk = 256 floats = one wave-wide float4 load). Per chunk:
//     4 ballots -> 4 u64 words. Convention: word[c*4+j] bit i <->
//     adj[chunk*256 + 4*i + j] (chunk = n*16+k -> col = k*256+4*i+j).
//     64 MB f32 -> 2 MB bitmask; no LDS, no scatter, no row serialization.
// Round-robin dispatch: each CU hosts ~1 qkv + 8 stream blocks.
// ---------------------------------------------------------------------------
__global__ __launch_bounds__(256) void prep2_kernel(
    const float* __restrict__ x,
    const float* __restrict__ Wq,
    const float* __restrict__ Wk,
    const float* __restrict__ Wv,
    const float* __restrict__ adj,
    float* __restrict__ q,
    unsigned short* __restrict__ kb,
    unsigned short* __restrict__ vb,
    unsigned long long* __restrict__ bm) {
  __shared__ short xs[64 * 128];  // 16KB bf16, swizzled (QKV role only)

  const int tid = threadIdx.x;
  const int w = tid >> 6;
  const int lane = tid & 63;
  const int bid = (int)blockIdx.x;

  if (bid < 256) {
    // ---------------- QKV via MFMA (R8 verbatim) ----------------
    const int row0 = bid * 64;
    const int half = lane >> 4;  // 0..3
    const int l16 = lane & 15;

    const float4* xg = (const float4*)(x + (size_t)row0 * Hh);
#pragma unroll
    for (int j = 0; j < 8; ++j) {
      const int idx = tid + 256 * j;  // float4 index; 32 per row
      const int row = idx >> 5;
      const int c4 = idx & 31;
      const float4 xv = xg[idx];
      uint2 p;
      p.x = (unsigned)f2bf(xv.x) | ((unsigned)f2bf(xv.y) << 16);
      p.y = (unsigned)f2bf(xv.z) | ((unsigned)f2bf(xv.w) << 16);
      const int addr = (row * 256 + c4 * 8) ^ ((row & 7) << 4);
      *(uint2*)((char*)xs + addr) = p;
    }

    bf16x8 bfr[3][4];
#pragma unroll
    for (int nt = 0; nt < 3; ++nt) {
      const int n0g = w * 48 + nt * 16;
      const float* Wm = (n0g < 64) ? Wq : (n0g < 128) ? Wk : Wv;
      const int c0 = n0g & 63;
#pragma unroll
      for (int ks = 0; ks < 4; ++ks) {
        bf16x8 f;
#pragma unroll
        for (int j = 0; j < 8; ++j) {
          const int kr = ks * 32 + half * 8 + j;
          f[j] = (short)f2bf(Wm[kr * Ff + c0 + l16]);
        }
        bfr[nt][ks] = f;
      }
    }
    __syncthreads();

    f32x4 acc[4][3];
#pragma unroll
    for (int mt = 0; mt < 4; ++mt)
#pragma unroll
      for (int nt = 0; nt < 3; ++nt)
#pragma unroll
        for (int r = 0; r < 4; ++r) acc[mt][nt][r] = 0.f;

#pragma unroll
    for (int mt = 0; mt < 4; ++mt) {
      const int arow = mt * 16 + l16;
      const int abase = arow * 256;
      const int aswz = (arow & 7) << 4;
#pragma unroll
      for (int ks = 0; ks < 4; ++ks) {
        const int addr = (abase + ks * 64 + half * 16) ^ aswz;
        const bf16x8 a = *(const bf16x8*)((const char*)xs + addr);
#pragma unroll
        for (int nt = 0; nt < 3; ++nt) {
          acc[mt][nt] = __builtin_amdgcn_mfma_f32_16x16x32_bf16(
              a, bfr[nt][ks], acc[mt][nt], 0, 0, 0);
        }
      }
    }

#pragma unroll
    for (int mt = 0; mt < 4; ++mt) {
#pragma unroll
      for (int nt = 0; nt < 3; ++nt) {
        const int n0g = w * 48 + nt * 16;
        const int col = (n0g & 63) + l16;
#pragma unroll
        for (int r = 0; r < 4; ++r) {
          const size_t rowg = (size_t)row0 + mt * 16 + half * 4 + r;
          const float val = acc[mt][nt][r];
          if (n0g < 64)
            q[rowg * Ff + col] = val;
          else if (n0g < 128)
            kb[rowg * Ff + col] = f2bf(val);
          else
            vb[rowg * Ff + col] = f2bf(val);
        }
      }
    }
  } else {
    // ---------------- pure bitmask stream ----------------
    const int sid = bid - 256;                 // [0, 2048)
    const int wg = sid * 4 + w;                // wave id [0, 8192)
    // 8 consecutive chunks per wave: chunks [wg*8, wg*8+8)
    const float4* base = ((const float4*)adj) + ((size_t)wg * 8) * 64 + lane;

    float4 a[8];
#pragma unroll
    for (int it = 0; it < 8; ++it) a[it] = base[it * 64];

#pragma unroll
    for (int it = 0; it < 8; ++it) {
      const unsigned long long b0 = __ballot(a[it].x != 0.f);
      const unsigned long long b1 = __ballot(a[it].y != 0.f);
      const unsigned long long b2 = __ballot(a[it].z != 0.f);
      const unsigned long long b3 = __ballot(a[it].w != 0.f);
      const unsigned long long bsel =
          lane == 0 ? b0 : lane == 1 ? b1 : lane == 2 ? b2 : b3;
      if (lane < 4) bm[((size_t)wg * 8 + it) * 4 + lane] = bsel;
    }
  }
}

// ---------------------------------------------------------------------------
// attn_kernel: bitmask-expand + sparse masked attention, bf16 k/v.
// One block (4 waves) per row n; wave w = batch b.
// Expand: wave 0 only. 64 lanes <-> 64 u64 words (512 B row read).
//   popcount -> shfl_up scan -> ctz-walk each word into LDS nbr (unordered;
//   order perturbs fp rounding only -- established R10).
//   word j = lane: k = j>>2, c = j&3; bit i -> col = k*256 + 4*i + c.
// Attention (verified verbatim): 4-lane-group k gather, line-minimal bf16
//   rows; group shfl(1,2) completes dots -> psum reduce spans GROUPS ONLY
//   (offsets 32..4; 2,1 would 4x-count: the R3 bug). PV: lane = feature.
// out = acc/L + sum_v (reference adds adj back: +1 per neighbor).
// ---------------------------------------------------------------------------
__global__ __launch_bounds__(256) void attn_kernel(
    const unsigned long long* __restrict__ bm,
    const float* __restrict__ q,
    const unsigned short* __restrict__ kb,
    const unsigned short* __restrict__ vb,
    float* __restrict__ out) {
  __shared__ __align__(8) unsigned short nbr[CAP];
  __shared__ float qs[4][64];
  __shared__ float ps[4][64];
  __shared__ int s_tot;

  const int n = blockIdx.x;
  const int tid = threadIdx.x;
  const int w = tid >> 6;
  const int lane = tid & 63;

  qs[w][lane] = q[((size_t)w * Nn + n) * Ff + lane];

  if (w == 0) {
    unsigned long long m = bm[(size_t)n * 64 + lane];  // coalesced 512B
    const int cnt = __popcll(m);
    int inc = cnt;
#pragma unroll
    for (int o = 1; o < 64; o <<= 1) {
      const int t = __shfl_up(inc, o, 64);
      if (lane >= o) inc += t;
    }
    int pos = inc - cnt;  // exclusive offset
    const int colbase = ((lane >> 2) << 8) + (lane & 3);
    while (m) {
      const int i = __builtin_ctzll(m);
      if (pos < CAP) nbr[pos] = (unsigned short)(colbase + (i << 2));
      ++pos;
      m &= m - 1;
    }
    if (lane == 63) s_tot = inc;
  }
  __syncthreads();

  const int tot = s_tot < CAP ? s_tot : CAP;

  const int b = w;
  const unsigned short* kbb = kb + (size_t)b * Nn * Ff;
  const unsigned short* vbb = vb + (size_t)b * Nn * Ff;

  const int g = lane >> 2;  // row group 0..15
  const int sl = lane & 3;  // sub-lane

  float4 q0a = *(const float4*)&qs[b][8 * sl];
  float4 q0b = *(const float4*)&qs[b][8 * sl + 4];
  float4 q1a = *(const float4*)&qs[b][32 + 8 * sl];
  float4 q1b = *(const float4*)&qs[b][32 + 8 * sl + 4];

  float M = -INFINITY, L = 0.f, acc = 0.f, vsum = 0.f;

  const int ntiles = (tot + 63) >> 6;
  for (int t = 0; t < ntiles; ++t) {
    const int tbase = t << 6;

    float s0, s1, s2, s3;
#define BPAIR(u, qlo, qhi, a)                                   \
    {                                                           \
      const float flo = __uint_as_float((u) << 16);             \
      const float fhi = __uint_as_float((u) & 0xffff0000u);     \
      a = fmaf(qlo, flo, a);                                    \
      a = fmaf(qhi, fhi, a);                                    \
    }
#define DOT_ROW(i, sdst)                                                  \
    {                                                                     \
      const int idx = tbase + g + 16 * (i);                               \
      const bool valid = idx < tot;                                       \
      const int m = valid ? (int)nbr[idx] : 0;                            \
      const char* krow = (const char*)(kbb + (size_t)m * Ff);             \
      const uint4 k0 = *(const uint4*)(krow + 16 * sl);                   \
      const uint4 k1 = *(const uint4*)(krow + 64 + 16 * sl);              \
      float a = 0.f;                                                      \
      BPAIR(k0.x, q0a.x, q0a.y, a)                                        \
      BPAIR(k0.y, q0a.z, q0a.w, a)                                        \
      BPAIR(k0.z, q0b.x, q0b.y, a)                                        \
      BPAIR(k0.w, q0b.z, q0b.w, a)                                        \
      BPAIR(k1.x, q1a.x, q1a.y, a)                                        \
      BPAIR(k1.y, q1a.z, q1a.w, a)                                        \
      BPAIR(k1.z, q1b.x, q1b.y, a)                                        \
      BPAIR(k1.w, q1b.z, q1b.w, a)                                        \
      a += __shfl_xor(a, 1, 64);                                          \
      a += __shfl_xor(a, 2, 64);                                          \
      sdst = valid ? a * 0.125f : -INFINITY;                              \
    }
    DOT_ROW(0, s0)
    DOT_ROW(1, s1)
    DOT_ROW(2, s2)
    DOT_ROW(3, s3)
#undef DOT_ROW
#undef BPAIR

    float lm = fmaxf(fmaxf(s0, s1), fmaxf(s2, s3));
#pragma unroll
    for (int o = 32; o; o >>= 1) lm = fmaxf(lm, __shfl_xor(lm, o, 64));
    const float newM = fmaxf(M, lm);

    const float p0 = (s0 == -INFINITY) ? 0.f : __expf(s0 - newM);
    const float p1 = (s1 == -INFINITY) ? 0.f : __expf(s1 - newM);
    const float p2 = (s2 == -INFINITY) ? 0.f : __expf(s2 - newM);
    const float p3 = (s3 == -INFINITY) ? 0.f : __expf(s3 - newM);

    float psum = ((p0 + p1) + (p2 + p3));
#pragma unroll
    for (int o = 32; o >= 4; o >>= 1) psum += __shfl_xor(psum, o, 64);

    const float corr = __expf(M - newM);  // t==0: exp(-inf)=0, L=acc=0
    L = L * corr + psum;
    acc *= corr;
    M = newM;

    const float pw = sl == 0 ? p0 : sl == 1 ? p1 : sl == 2 ? p2 : p3;
    ps[w][g + 16 * sl] = pw;

    const int jmax = min(64, tot - tbase);
#pragma unroll 4
    for (int j = 0; j < jmax; ++j) {
      const int m = nbr[tbase + j];                       // LDS broadcast
      const float vf = bf2f(vbb[(size_t)m * Ff + lane]);  // coalesced 128B
      acc = fmaf(ps[w][j], vf, acc);                      // p broadcast
      vsum += vf;
    }
  }

  out[((size_t)b * Nn + n) * Ff + lane] = acc / L + vsum;
}

// ---------------------------------------------------------------------------
extern "C" void kernel_launch(void* const* d_in, const int* in_sizes, int n_in,
                              void* d_out, int out_size, void* d_ws, size_t ws_size,
                              hipStream_t stream) {
  const float* x = (const float*)d_in[0];
  const float* Wq = (const float*)d_in[1];
  const float* Wk = (const float*)d_in[2];
  const float* Wv = (const float*)d_in[3];
  const float* adj = (const float*)d_in[4];
  float* out = (float*)d_out;

  char* ws = (char*)d_ws;
  const size_t rows = (size_t)Bb * Nn;  // 16384
  float* q = (float*)ws;                                       // 4 MiB
  unsigned short* kb = (unsigned short*)(ws + rows * Ff * 4);  // 2 MiB
  unsigned short* vb = (unsigned short*)(ws + rows * Ff * 4 + rows * Ff * 2);
  unsigned long long* bm = (unsigned long long*)(ws + rows * Ff * 8);  // 2 MiB

  prep2_kernel<<<dim3(2304), dim3(256), 0, stream>>>(
      x, Wq, Wk, Wv, adj, q, kb, vb, bm);
  attn_kernel<<<dim3(Nn), dim3(256), 0, stream>>>(bm, q, kb, vb, out);
}